// Round 11
// baseline (187.950 us; speedup 1.0000x reference)
//
#include <hip/hip_runtime.h>
#include <hip/hip_bf16.h>
#include <cstddef>

constexpr int C = 64;   // channels
constexpr int B = 16;   // segments

typedef __attribute__((ext_vector_type(8))) short bf16x8;
typedef __attribute__((ext_vector_type(4))) float f32x4;
typedef __attribute__((ext_vector_type(4))) unsigned int u32x4;

__device__ inline unsigned short f2bf(float f) {
    unsigned u = __builtin_bit_cast(unsigned, f);
    unsigned r = (u + 0x7FFFu + ((u >> 16) & 1u)) >> 16;   // RNE
    return (unsigned short)r;
}

__device__ inline unsigned pk2(float a, float b) {
    __hip_bfloat162 t = __float22bfloat162_rn(float2{a, b});   // v_cvt_pk_bf16_f32
    unsigned u;
    __builtin_memcpy(&u, &t, 4);
    return u;
}

__device__ inline bf16x8 cvt8(float4 u, float4 v) {
    u32x4 r;
    r[0] = pk2(u.x, u.y);
    r[1] = pk2(u.z, u.w);
    r[2] = pk2(v.x, v.y);
    r[3] = pk2(v.z, v.w);
    return __builtin_bit_cast(bf16x8, r);
}

// ---------------- Kernel A: per-segment column sums (R6-exact) ----------------
__global__ __launch_bounds__(256) void seg_sum_kernel(
    const float* __restrict__ x, const int* __restrict__ o,
    float* __restrict__ sums, int N, int rows_per_block)
{
    __shared__ float lsum[B * C];
    const int tid = threadIdx.x;
    for (int i = tid; i < B * C; i += 256) lsum[i] = 0.0f;
    __syncthreads();

    const int c4 = (tid & 15) * 4;
    const int r0 = tid >> 4;
    const int row_begin = blockIdx.x * rows_per_block;
    const int row_end   = min(N, row_begin + rows_per_block);

    float ax = 0.f, ay = 0.f, az = 0.f, aw = 0.f;
    int seg = 0;
    int endcur = o[0];

    for (int r = row_begin + r0; r < row_end; r += 16) {
        while (r >= endcur) {
            if (ax != 0.f || ay != 0.f || az != 0.f || aw != 0.f) {
                atomicAdd(&lsum[seg * C + c4 + 0], ax);
                atomicAdd(&lsum[seg * C + c4 + 1], ay);
                atomicAdd(&lsum[seg * C + c4 + 2], az);
                atomicAdd(&lsum[seg * C + c4 + 3], aw);
                ax = ay = az = aw = 0.f;
            }
            ++seg;
            endcur = o[seg];
        }
        const float4 v = *reinterpret_cast<const float4*>(x + (size_t)r * C + c4);
        ax += v.x; ay += v.y; az += v.z; aw += v.w;
    }
    if (ax != 0.f || ay != 0.f || az != 0.f || aw != 0.f) {
        atomicAdd(&lsum[seg * C + c4 + 0], ax);
        atomicAdd(&lsum[seg * C + c4 + 1], ay);
        atomicAdd(&lsum[seg * C + c4 + 2], az);
        atomicAdd(&lsum[seg * C + c4 + 3], aw);
    }
    __syncthreads();

    for (int i = tid; i < B * C; i += 256) {
        const float v = lsum[i];
        if (v != 0.f) atomicAdd(&sums[i], v);
    }
}

// ---------------- Kernel C: fused MLP-prologue + MFMA main pass ----------------
// R10 structure (LDS-squeezed to ~12.2KB -> 8 blocks/CU); single change vs R10:
// out stores are PLAIN float4 (A/B: nontemporal bypass vs L2 write-back drain).
__global__ __launch_bounds__(256) void main_mfma_kernel(
    const float* __restrict__ x, const int* __restrict__ o,
    const float* __restrict__ sums,
    const float* __restrict__ W2, const float* __restrict__ b2,
    const float* __restrict__ W1, const float* __restrict__ b1,
    const float* __restrict__ gamma, const float* __restrict__ beta,
    float* __restrict__ out, int N, int rows_per_wave, int ngw)
{
    __shared__ float smem[3 * B * C];
    __shared__ int osh[B];
    float* ms  = smem;                 // means
    float* xbs = smem + B * C;         // hidden
    float* vl  = smem + 2 * B * C;     // per-segment bias table
    unsigned short* wbfs = (unsigned short*)smem;  // 4096 bf16 = 8KB over ms+xbs

    const int tid = threadIdx.x;
    if (tid < B) osh[tid] = o[tid];
    __syncthreads();

    const int j = tid & 63;                // fixed channel per thread
    const int bq = tid >> 6;               // 0..3: quarter of segments

#pragma unroll
    for (int q = 0; q < 4; ++q) {
        const int b = bq * 4 + q;
        const int cnt = osh[b] - (b ? osh[b - 1] : 0);
        ms[b * C + j] = sums[b * C + j] / (float)cnt;
    }
    __syncthreads();

    {
        float acc[4];
        const float bj = b2[j];
#pragma unroll
        for (int q = 0; q < 4; ++q) acc[q] = bj;
        for (int c = 0; c < C; ++c) {
            const float wv = W2[c * C + j];
#pragma unroll
            for (int q = 0; q < 4; ++q)
                acc[q] = fmaf(ms[(bq * 4 + q) * C + c], wv, acc[q]);
        }
        __syncthreads();
#pragma unroll
        for (int q = 0; q < 4; ++q) xbs[(bq * 4 + q) * C + j] = fmaxf(acc[q], 0.f);
    }
    __syncthreads();

    {
        float acc[4];
        const float bj = b1[j];
#pragma unroll
        for (int q = 0; q < 4; ++q) acc[q] = bj;
        for (int jj = 0; jj < C; ++jj) {
            const float wv = W1[(C + jj) * C + j];
#pragma unroll
            for (int q = 0; q < 4; ++q)
                acc[q] = fmaf(xbs[(bq * 4 + q) * C + jj], wv, acc[q]);
        }
#pragma unroll
        for (int q = 0; q < 4; ++q) vl[(bq * 4 + q) * C + j] = acc[q];
    }
    __syncthreads();   // xbs dead from here; wbfs may overwrite ms+xbs

    for (int idx = tid; idx < 4096; idx += 256) {
        const int jj2 = idx & 7;
        const int ln  = (idx >> 3) & 63;
        const int tt  = (idx >> 9) & 1;
        const int ct  = idx >> 10;
        const int k   = tt * 32 + ((ln >> 4) * 8) + jj2;
        const int ch  = 4 * (ln & 15) + ct;          // permuted channel
        wbfs[idx] = f2bf(W1[k * C + ch]);
    }
    __syncthreads();

    const int lane = tid & 63;
    const int wid  = tid >> 6;
    const int chb  = lane & 15;
    const int prow = (lane >> 4) * 4;

    bf16x8 wf[4][2];
#pragma unroll
    for (int ct = 0; ct < 4; ++ct)
#pragma unroll
        for (int t = 0; t < 2; ++t)
            wf[ct][t] = *reinterpret_cast<const bf16x8*>(wbfs + ((ct * 2 + t) * 64 + lane) * 8);

    const float4 g4  = *reinterpret_cast<const float4*>(gamma + 4 * chb);
    const float4 bt4 = *reinterpret_cast<const float4*>(beta  + 4 * chb);

    const int gw = blockIdx.x * 4 + wid;
    if (gw >= ngw) return;
    const int p_begin = gw * rows_per_wave;
    if (p_begin >= N) return;
    const int p_end = min(N, p_begin + rows_per_wave);

    int seg = 0;
    while (p_begin >= osh[seg]) ++seg;
    float4 vb = *reinterpret_cast<const float4*>(vl + seg * C + 4 * chb);

    for (int p0 = p_begin; p0 < p_end; p0 += 16) {
        const float* xr = x + (size_t)(p0 + chb) * C + ((lane >> 4) * 8);
        const float4 a0 = *reinterpret_cast<const float4*>(xr);
        const float4 a1 = *reinterpret_cast<const float4*>(xr + 4);
        const float4 a2 = *reinterpret_cast<const float4*>(xr + 32);
        const float4 a3 = *reinterpret_cast<const float4*>(xr + 36);
        const bf16x8 A0 = cvt8(a0, a1);
        const bf16x8 A1 = cvt8(a2, a3);

        f32x4 acc[4];
#pragma unroll
        for (int ct = 0; ct < 4; ++ct) {
            acc[ct] = f32x4{0.f, 0.f, 0.f, 0.f};
            acc[ct] = __builtin_amdgcn_mfma_f32_16x16x32_bf16(A0, wf[ct][0], acc[ct], 0, 0, 0);
            acc[ct] = __builtin_amdgcn_mfma_f32_16x16x32_bf16(A1, wf[ct][1], acc[ct], 0, 0, 0);
        }

        float h[4][4];   // [ct][reg]
        if (p0 + 16 <= osh[seg]) {
#pragma unroll
            for (int r = 0; r < 4; ++r) {
                h[0][r] = acc[0][r] + vb.x;
                h[1][r] = acc[1][r] + vb.y;
                h[2][r] = acc[2][r] + vb.z;
                h[3][r] = acc[3][r] + vb.w;
            }
        } else {
#pragma unroll
            for (int r = 0; r < 4; ++r) {
                const int p = p0 + prow + r;
                int s = seg;
                while (p >= osh[s]) ++s;
                const float4 vbs = *reinterpret_cast<const float4*>(vl + s * C + 4 * chb);
                h[0][r] = acc[0][r] + vbs.x;
                h[1][r] = acc[1][r] + vbs.y;
                h[2][r] = acc[2][r] + vbs.z;
                h[3][r] = acc[3][r] + vbs.w;
            }
        }

#pragma unroll
        for (int r = 0; r < 4; ++r) {
            float s_ = (h[0][r] + h[1][r]) + (h[2][r] + h[3][r]);
            float q_ = fmaf(h[0][r], h[0][r],
                       fmaf(h[1][r], h[1][r],
                       fmaf(h[2][r], h[2][r], h[3][r] * h[3][r])));
#pragma unroll
            for (int m = 1; m < 16; m <<= 1) {
                s_ += __shfl_xor(s_, m, 64);
                q_ += __shfl_xor(q_, m, 64);
            }
            const float mean = s_ * (1.0f / 64.0f);
            const float var  = q_ * (1.0f / 64.0f) - mean * mean;
            const float rs   = rsqrtf(var + 1e-5f);
            const int p = p0 + prow + r;

            float4 y;
            y.x = fmaxf((h[0][r] - mean) * rs * g4.x + bt4.x, 0.f);
            y.y = fmaxf((h[1][r] - mean) * rs * g4.y + bt4.y, 0.f);
            y.z = fmaxf((h[2][r] - mean) * rs * g4.z + bt4.z, 0.f);
            y.w = fmaxf((h[3][r] - mean) * rs * g4.w + bt4.w, 0.f);
            *reinterpret_cast<float4*>(out + (size_t)p * C + 4 * chb) = y;   // plain store (A/B vs nt)
        }

        const int pn = p0 + 16;
        if (pn < p_end && pn >= osh[seg]) {
            while (pn >= osh[seg]) ++seg;
            vb = *reinterpret_cast<const float4*>(vl + seg * C + 4 * chb);
        }
    }
}

extern "C" void kernel_launch(void* const* d_in, const int* in_sizes, int n_in,
                              void* d_out, int out_size, void* d_ws, size_t ws_size,
                              hipStream_t stream) {
    const float* x     = (const float*)d_in[0];
    const int*   o     = (const int*)d_in[1];
    const float* W2    = (const float*)d_in[2];
    const float* b2    = (const float*)d_in[3];
    const float* W1    = (const float*)d_in[4];
    const float* b1    = (const float*)d_in[5];
    const float* gamma = (const float*)d_in[6];
    const float* beta  = (const float*)d_in[7];
    float* out = (float*)d_out;

    const int N = in_sizes[0] / C;

    float* sums = (float*)d_ws;   // 1024 f32

    (void)hipMemsetAsync(sums, 0, B * C * sizeof(float), stream);

    const int rpb = 512;
    const int gridA = (N + rpb - 1) / rpb;
    seg_sum_kernel<<<gridA, 256, 0, stream>>>(x, o, sums, N, rpb);

    const int rpw = 128;
    const int ngw = (N + rpw - 1) / rpw;
    const int gridC = (ngw + 3) / 4;
    main_mfma_kernel<<<gridC, 256, 0, stream>>>(x, o, sums, W2, b2, W1, b1,
                                                gamma, beta, out, N, rpw, ngw);
}

// Round 12
// 181.309 us; speedup vs baseline: 1.0366x; 1.0366x over previous
//
#include <hip/hip_runtime.h>
#include <hip/hip_bf16.h>
#include <cstddef>

constexpr int C = 64;   // channels
constexpr int B = 16;   // segments

typedef __attribute__((ext_vector_type(8))) short bf16x8;
typedef __attribute__((ext_vector_type(4))) float f32x4;
typedef __attribute__((ext_vector_type(4))) unsigned int u32x4;

__device__ inline unsigned short f2bf(float f) {
    unsigned u = __builtin_bit_cast(unsigned, f);
    unsigned r = (u + 0x7FFFu + ((u >> 16) & 1u)) >> 16;   // RNE
    return (unsigned short)r;
}

__device__ inline unsigned pk2(float a, float b) {
    __hip_bfloat162 t = __float22bfloat162_rn(float2{a, b});   // v_cvt_pk_bf16_f32
    unsigned u;
    __builtin_memcpy(&u, &t, 4);
    return u;
}

__device__ inline bf16x8 cvt8v(f32x4 u, f32x4 v) {
    u32x4 r;
    r[0] = pk2(u[0], u[1]);
    r[1] = pk2(u[2], u[3]);
    r[2] = pk2(v[0], v[1]);
    r[3] = pk2(v[2], v[3]);
    return __builtin_bit_cast(bf16x8, r);
}

__device__ inline f32x4 ntload4(const float* p) {
    return __builtin_nontemporal_load(reinterpret_cast<const f32x4*>(p));
}

// ---------------- Kernel A: per-segment column sums ----------------
// R10 structure; x loads NONTEMPORAL (x has no reuse anywhere - R8 proved it).
__global__ __launch_bounds__(256) void seg_sum_kernel(
    const float* __restrict__ x, const int* __restrict__ o,
    float* __restrict__ sums, int N, int rows_per_block)
{
    __shared__ float lsum[B * C];
    const int tid = threadIdx.x;
    for (int i = tid; i < B * C; i += 256) lsum[i] = 0.0f;
    __syncthreads();

    const int c4 = (tid & 15) * 4;
    const int r0 = tid >> 4;
    const int row_begin = blockIdx.x * rows_per_block;
    const int row_end   = min(N, row_begin + rows_per_block);

    float ax = 0.f, ay = 0.f, az = 0.f, aw = 0.f;
    int seg = 0;
    int endcur = o[0];

    for (int r = row_begin + r0; r < row_end; r += 16) {
        while (r >= endcur) {
            if (ax != 0.f || ay != 0.f || az != 0.f || aw != 0.f) {
                atomicAdd(&lsum[seg * C + c4 + 0], ax);
                atomicAdd(&lsum[seg * C + c4 + 1], ay);
                atomicAdd(&lsum[seg * C + c4 + 2], az);
                atomicAdd(&lsum[seg * C + c4 + 3], aw);
                ax = ay = az = aw = 0.f;
            }
            ++seg;
            endcur = o[seg];
        }
        const f32x4 v = ntload4(x + (size_t)r * C + c4);
        ax += v[0]; ay += v[1]; az += v[2]; aw += v[3];
    }
    if (ax != 0.f || ay != 0.f || az != 0.f || aw != 0.f) {
        atomicAdd(&lsum[seg * C + c4 + 0], ax);
        atomicAdd(&lsum[seg * C + c4 + 1], ay);
        atomicAdd(&lsum[seg * C + c4 + 2], az);
        atomicAdd(&lsum[seg * C + c4 + 3], aw);
    }
    __syncthreads();

    for (int i = tid; i < B * C; i += 256) {
        const float v = lsum[i];
        if (v != 0.f) atomicAdd(&sums[i], v);
    }
}

// ---------------- Kernel C: fused MLP-prologue + MFMA main pass ----------------
// R10 structure (LDS-squeeze -> 8 blocks/CU, nt float4 stores) + nt x loads.
__global__ __launch_bounds__(256) void main_mfma_kernel(
    const float* __restrict__ x, const int* __restrict__ o,
    const float* __restrict__ sums,
    const float* __restrict__ W2, const float* __restrict__ b2,
    const float* __restrict__ W1, const float* __restrict__ b1,
    const float* __restrict__ gamma, const float* __restrict__ beta,
    float* __restrict__ out, int N, int rows_per_wave, int ngw)
{
    __shared__ float smem[3 * B * C];
    __shared__ int osh[B];
    float* ms  = smem;                 // means
    float* xbs = smem + B * C;         // hidden
    float* vl  = smem + 2 * B * C;     // per-segment bias table
    unsigned short* wbfs = (unsigned short*)smem;  // 4096 bf16 = 8KB over ms+xbs

    const int tid = threadIdx.x;
    if (tid < B) osh[tid] = o[tid];
    __syncthreads();

    const int j = tid & 63;                // fixed channel per thread
    const int bq = tid >> 6;               // 0..3: quarter of segments

#pragma unroll
    for (int q = 0; q < 4; ++q) {
        const int b = bq * 4 + q;
        const int cnt = osh[b] - (b ? osh[b - 1] : 0);
        ms[b * C + j] = sums[b * C + j] / (float)cnt;
    }
    __syncthreads();

    {
        float acc[4];
        const float bj = b2[j];
#pragma unroll
        for (int q = 0; q < 4; ++q) acc[q] = bj;
        for (int c = 0; c < C; ++c) {
            const float wv = W2[c * C + j];
#pragma unroll
            for (int q = 0; q < 4; ++q)
                acc[q] = fmaf(ms[(bq * 4 + q) * C + c], wv, acc[q]);
        }
        __syncthreads();
#pragma unroll
        for (int q = 0; q < 4; ++q) xbs[(bq * 4 + q) * C + j] = fmaxf(acc[q], 0.f);
    }
    __syncthreads();

    {
        float acc[4];
        const float bj = b1[j];
#pragma unroll
        for (int q = 0; q < 4; ++q) acc[q] = bj;
        for (int jj = 0; jj < C; ++jj) {
            const float wv = W1[(C + jj) * C + j];
#pragma unroll
            for (int q = 0; q < 4; ++q)
                acc[q] = fmaf(xbs[(bq * 4 + q) * C + jj], wv, acc[q]);
        }
#pragma unroll
        for (int q = 0; q < 4; ++q) vl[(bq * 4 + q) * C + j] = acc[q];
    }
    __syncthreads();   // xbs dead from here; wbfs may overwrite ms+xbs

    for (int idx = tid; idx < 4096; idx += 256) {
        const int jj2 = idx & 7;
        const int ln  = (idx >> 3) & 63;
        const int tt  = (idx >> 9) & 1;
        const int ct  = idx >> 10;
        const int k   = tt * 32 + ((ln >> 4) * 8) + jj2;
        const int ch  = 4 * (ln & 15) + ct;          // permuted channel
        wbfs[idx] = f2bf(W1[k * C + ch]);
    }
    __syncthreads();

    const int lane = tid & 63;
    const int wid  = tid >> 6;
    const int chb  = lane & 15;
    const int prow = (lane >> 4) * 4;

    bf16x8 wf[4][2];
#pragma unroll
    for (int ct = 0; ct < 4; ++ct)
#pragma unroll
        for (int t = 0; t < 2; ++t)
            wf[ct][t] = *reinterpret_cast<const bf16x8*>(wbfs + ((ct * 2 + t) * 64 + lane) * 8);

    const float4 g4  = *reinterpret_cast<const float4*>(gamma + 4 * chb);
    const float4 bt4 = *reinterpret_cast<const float4*>(beta  + 4 * chb);

    const int gw = blockIdx.x * 4 + wid;
    if (gw >= ngw) return;
    const int p_begin = gw * rows_per_wave;
    if (p_begin >= N) return;
    const int p_end = min(N, p_begin + rows_per_wave);

    int seg = 0;
    while (p_begin >= osh[seg]) ++seg;
    float4 vb = *reinterpret_cast<const float4*>(vl + seg * C + 4 * chb);

    for (int p0 = p_begin; p0 < p_end; p0 += 16) {
        const float* xr = x + (size_t)(p0 + chb) * C + ((lane >> 4) * 8);
        const f32x4 a0 = ntload4(xr);
        const f32x4 a1 = ntload4(xr + 4);
        const f32x4 a2 = ntload4(xr + 32);
        const f32x4 a3 = ntload4(xr + 36);
        const bf16x8 A0 = cvt8v(a0, a1);
        const bf16x8 A1 = cvt8v(a2, a3);

        f32x4 acc[4];
#pragma unroll
        for (int ct = 0; ct < 4; ++ct) {
            acc[ct] = f32x4{0.f, 0.f, 0.f, 0.f};
            acc[ct] = __builtin_amdgcn_mfma_f32_16x16x32_bf16(A0, wf[ct][0], acc[ct], 0, 0, 0);
            acc[ct] = __builtin_amdgcn_mfma_f32_16x16x32_bf16(A1, wf[ct][1], acc[ct], 0, 0, 0);
        }

        float h[4][4];   // [ct][reg]
        if (p0 + 16 <= osh[seg]) {
#pragma unroll
            for (int r = 0; r < 4; ++r) {
                h[0][r] = acc[0][r] + vb.x;
                h[1][r] = acc[1][r] + vb.y;
                h[2][r] = acc[2][r] + vb.z;
                h[3][r] = acc[3][r] + vb.w;
            }
        } else {
#pragma unroll
            for (int r = 0; r < 4; ++r) {
                const int p = p0 + prow + r;
                int s = seg;
                while (p >= osh[s]) ++s;
                const float4 vbs = *reinterpret_cast<const float4*>(vl + s * C + 4 * chb);
                h[0][r] = acc[0][r] + vbs.x;
                h[1][r] = acc[1][r] + vbs.y;
                h[2][r] = acc[2][r] + vbs.z;
                h[3][r] = acc[3][r] + vbs.w;
            }
        }

#pragma unroll
        for (int r = 0; r < 4; ++r) {
            float s_ = (h[0][r] + h[1][r]) + (h[2][r] + h[3][r]);
            float q_ = fmaf(h[0][r], h[0][r],
                       fmaf(h[1][r], h[1][r],
                       fmaf(h[2][r], h[2][r], h[3][r] * h[3][r])));
#pragma unroll
            for (int m = 1; m < 16; m <<= 1) {
                s_ += __shfl_xor(s_, m, 64);
                q_ += __shfl_xor(q_, m, 64);
            }
            const float mean = s_ * (1.0f / 64.0f);
            const float var  = q_ * (1.0f / 64.0f) - mean * mean;
            const float rs   = rsqrtf(var + 1e-5f);
            const int p = p0 + prow + r;

            f32x4 y;
            y[0] = fmaxf((h[0][r] - mean) * rs * g4.x + bt4.x, 0.f);
            y[1] = fmaxf((h[1][r] - mean) * rs * g4.y + bt4.y, 0.f);
            y[2] = fmaxf((h[2][r] - mean) * rs * g4.z + bt4.z, 0.f);
            y[3] = fmaxf((h[3][r] - mean) * rs * g4.w + bt4.w, 0.f);
            __builtin_nontemporal_store(y, reinterpret_cast<f32x4*>(out + (size_t)p * C + 4 * chb));
        }

        const int pn = p0 + 16;
        if (pn < p_end && pn >= osh[seg]) {
            while (pn >= osh[seg]) ++seg;
            vb = *reinterpret_cast<const float4*>(vl + seg * C + 4 * chb);
        }
    }
}

extern "C" void kernel_launch(void* const* d_in, const int* in_sizes, int n_in,
                              void* d_out, int out_size, void* d_ws, size_t ws_size,
                              hipStream_t stream) {
    const float* x     = (const float*)d_in[0];
    const int*   o     = (const int*)d_in[1];
    const float* W2    = (const float*)d_in[2];
    const float* b2    = (const float*)d_in[3];
    const float* W1    = (const float*)d_in[4];
    const float* b1    = (const float*)d_in[5];
    const float* gamma = (const float*)d_in[6];
    const float* beta  = (const float*)d_in[7];
    float* out = (float*)d_out;

    const int N = in_sizes[0] / C;

    float* sums = (float*)d_ws;   // 1024 f32

    (void)hipMemsetAsync(sums, 0, B * C * sizeof(float), stream);

    const int rpb = 512;
    const int gridA = (N + rpb - 1) / rpb;
    seg_sum_kernel<<<gridA, 256, 0, stream>>>(x, o, sums, N, rpb);

    const int rpw = 128;
    const int ngw = (N + rpw - 1) / rpw;
    const int gridC = (ngw + 3) / 4;
    main_mfma_kernel<<<gridC, 256, 0, stream>>>(x, o, sums, W2, b2, W1, b1,
                                                gamma, beta, out, N, rpw, ngw);
}

// Round 13
// 154.750 us; speedup vs baseline: 1.2145x; 1.1716x over previous
//
#include <hip/hip_runtime.h>
#include <hip/hip_bf16.h>
#include <cstddef>

constexpr int C = 64;   // channels
constexpr int B = 16;   // segments

typedef __attribute__((ext_vector_type(8))) short bf16x8;
typedef __attribute__((ext_vector_type(4))) float f32x4;
typedef __attribute__((ext_vector_type(4))) unsigned int u32x4;

__device__ inline unsigned short f2bf(float f) {
    unsigned u = __builtin_bit_cast(unsigned, f);
    unsigned r = (u + 0x7FFFu + ((u >> 16) & 1u)) >> 16;   // RNE
    return (unsigned short)r;
}

__device__ inline unsigned pk2(float a, float b) {
    __hip_bfloat162 t = __float22bfloat162_rn(float2{a, b});   // v_cvt_pk_bf16_f32
    unsigned u;
    __builtin_memcpy(&u, &t, 4);
    return u;
}

__device__ inline bf16x8 cvt8(float4 u, float4 v) {
    u32x4 r;
    r[0] = pk2(u.x, u.y);
    r[1] = pk2(u.z, u.w);
    r[2] = pk2(v.x, v.y);
    r[3] = pk2(v.z, v.w);
    return __builtin_bit_cast(bf16x8, r);
}

// ---------------- Kernel A: per-segment column sums ----------------
// 8 col-groups (8 channels) x 32 row-offsets: 2 independent float4 loads per
// iteration (deeper read pipeline). Normal cached loads (nt loads proven -30us).
__global__ __launch_bounds__(256) void seg_sum_kernel(
    const float* __restrict__ x, const int* __restrict__ o,
    float* __restrict__ sums, int N, int rows_per_block)
{
    __shared__ float lsum[B * C];
    const int tid = threadIdx.x;
    for (int i = tid; i < B * C; i += 256) lsum[i] = 0.0f;
    __syncthreads();

    const int c8 = (tid & 7) * 8;      // 8 consecutive channels
    const int r0 = tid >> 3;           // 0..31 row offset
    const int row_begin = blockIdx.x * rows_per_block;
    const int row_end   = min(N, row_begin + rows_per_block);

    float a[8];
#pragma unroll
    for (int i = 0; i < 8; ++i) a[i] = 0.f;
    int seg = 0;
    int endcur = o[0];

    for (int r = row_begin + r0; r < row_end; r += 32) {
        while (r >= endcur) {
#pragma unroll
            for (int i = 0; i < 8; ++i)
                if (a[i] != 0.f) { atomicAdd(&lsum[seg * C + c8 + i], a[i]); a[i] = 0.f; }
            ++seg;
            endcur = o[seg];
        }
        const float4 v0 = *reinterpret_cast<const float4*>(x + (size_t)r * C + c8);
        const float4 v1 = *reinterpret_cast<const float4*>(x + (size_t)r * C + c8 + 4);
        a[0] += v0.x; a[1] += v0.y; a[2] += v0.z; a[3] += v0.w;
        a[4] += v1.x; a[5] += v1.y; a[6] += v1.z; a[7] += v1.w;
    }
#pragma unroll
    for (int i = 0; i < 8; ++i)
        if (a[i] != 0.f) atomicAdd(&lsum[seg * C + c8 + i], a[i]);
    __syncthreads();

    for (int i = tid; i < B * C; i += 256) {
        const float v = lsum[i];
        if (v != 0.f) atomicAdd(&sums[i], v);
    }
}

// ---------------- Kernel C: fused MLP-prologue + MFMA main pass (R10-exact) ----
// LDS-squeezed (~12.2KB -> 8 blocks/CU); normal x loads; NT out stores.
__global__ __launch_bounds__(256) void main_mfma_kernel(
    const float* __restrict__ x, const int* __restrict__ o,
    const float* __restrict__ sums,
    const float* __restrict__ W2, const float* __restrict__ b2,
    const float* __restrict__ W1, const float* __restrict__ b1,
    const float* __restrict__ gamma, const float* __restrict__ beta,
    float* __restrict__ out, int N, int rows_per_wave, int ngw)
{
    __shared__ float smem[3 * B * C];
    __shared__ int osh[B];
    float* ms  = smem;                 // means
    float* xbs = smem + B * C;         // hidden
    float* vl  = smem + 2 * B * C;     // per-segment bias table
    unsigned short* wbfs = (unsigned short*)smem;  // 4096 bf16 = 8KB over ms+xbs

    const int tid = threadIdx.x;
    if (tid < B) osh[tid] = o[tid];
    __syncthreads();

    const int j = tid & 63;                // fixed channel per thread
    const int bq = tid >> 6;               // 0..3: quarter of segments

#pragma unroll
    for (int q = 0; q < 4; ++q) {
        const int b = bq * 4 + q;
        const int cnt = osh[b] - (b ? osh[b - 1] : 0);
        ms[b * C + j] = sums[b * C + j] / (float)cnt;
    }
    __syncthreads();

    {
        float acc[4];
        const float bj = b2[j];
#pragma unroll
        for (int q = 0; q < 4; ++q) acc[q] = bj;
        for (int c = 0; c < C; ++c) {
            const float wv = W2[c * C + j];
#pragma unroll
            for (int q = 0; q < 4; ++q)
                acc[q] = fmaf(ms[(bq * 4 + q) * C + c], wv, acc[q]);
        }
        __syncthreads();
#pragma unroll
        for (int q = 0; q < 4; ++q) xbs[(bq * 4 + q) * C + j] = fmaxf(acc[q], 0.f);
    }
    __syncthreads();

    {
        float acc[4];
        const float bj = b1[j];
#pragma unroll
        for (int q = 0; q < 4; ++q) acc[q] = bj;
        for (int jj = 0; jj < C; ++jj) {
            const float wv = W1[(C + jj) * C + j];
#pragma unroll
            for (int q = 0; q < 4; ++q)
                acc[q] = fmaf(xbs[(bq * 4 + q) * C + jj], wv, acc[q]);
        }
#pragma unroll
        for (int q = 0; q < 4; ++q) vl[(bq * 4 + q) * C + j] = acc[q];
    }
    __syncthreads();   // xbs dead from here; wbfs may overwrite ms+xbs

    for (int idx = tid; idx < 4096; idx += 256) {
        const int jj2 = idx & 7;
        const int ln  = (idx >> 3) & 63;
        const int tt  = (idx >> 9) & 1;
        const int ct  = idx >> 10;
        const int k   = tt * 32 + ((ln >> 4) * 8) + jj2;
        const int ch  = 4 * (ln & 15) + ct;          // permuted channel
        wbfs[idx] = f2bf(W1[k * C + ch]);
    }
    __syncthreads();

    const int lane = tid & 63;
    const int wid  = tid >> 6;
    const int chb  = lane & 15;
    const int prow = (lane >> 4) * 4;

    bf16x8 wf[4][2];
#pragma unroll
    for (int ct = 0; ct < 4; ++ct)
#pragma unroll
        for (int t = 0; t < 2; ++t)
            wf[ct][t] = *reinterpret_cast<const bf16x8*>(wbfs + ((ct * 2 + t) * 64 + lane) * 8);

    const float4 g4  = *reinterpret_cast<const float4*>(gamma + 4 * chb);
    const float4 bt4 = *reinterpret_cast<const float4*>(beta  + 4 * chb);

    const int gw = blockIdx.x * 4 + wid;
    if (gw >= ngw) return;
    const int p_begin = gw * rows_per_wave;
    if (p_begin >= N) return;
    const int p_end = min(N, p_begin + rows_per_wave);

    int seg = 0;
    while (p_begin >= osh[seg]) ++seg;
    float4 vb = *reinterpret_cast<const float4*>(vl + seg * C + 4 * chb);

    for (int p0 = p_begin; p0 < p_end; p0 += 16) {
        const float* xr = x + (size_t)(p0 + chb) * C + ((lane >> 4) * 8);
        const float4 a0 = *reinterpret_cast<const float4*>(xr);
        const float4 a1 = *reinterpret_cast<const float4*>(xr + 4);
        const float4 a2 = *reinterpret_cast<const float4*>(xr + 32);
        const float4 a3 = *reinterpret_cast<const float4*>(xr + 36);
        const bf16x8 A0 = cvt8(a0, a1);
        const bf16x8 A1 = cvt8(a2, a3);

        f32x4 acc[4];
#pragma unroll
        for (int ct = 0; ct < 4; ++ct) {
            acc[ct] = f32x4{0.f, 0.f, 0.f, 0.f};
            acc[ct] = __builtin_amdgcn_mfma_f32_16x16x32_bf16(A0, wf[ct][0], acc[ct], 0, 0, 0);
            acc[ct] = __builtin_amdgcn_mfma_f32_16x16x32_bf16(A1, wf[ct][1], acc[ct], 0, 0, 0);
        }

        float h[4][4];   // [ct][reg]
        if (p0 + 16 <= osh[seg]) {
#pragma unroll
            for (int r = 0; r < 4; ++r) {
                h[0][r] = acc[0][r] + vb.x;
                h[1][r] = acc[1][r] + vb.y;
                h[2][r] = acc[2][r] + vb.z;
                h[3][r] = acc[3][r] + vb.w;
            }
        } else {
#pragma unroll
            for (int r = 0; r < 4; ++r) {
                const int p = p0 + prow + r;
                int s = seg;
                while (p >= osh[s]) ++s;
                const float4 vbs = *reinterpret_cast<const float4*>(vl + s * C + 4 * chb);
                h[0][r] = acc[0][r] + vbs.x;
                h[1][r] = acc[1][r] + vbs.y;
                h[2][r] = acc[2][r] + vbs.z;
                h[3][r] = acc[3][r] + vbs.w;
            }
        }

#pragma unroll
        for (int r = 0; r < 4; ++r) {
            float s_ = (h[0][r] + h[1][r]) + (h[2][r] + h[3][r]);
            float q_ = fmaf(h[0][r], h[0][r],
                       fmaf(h[1][r], h[1][r],
                       fmaf(h[2][r], h[2][r], h[3][r] * h[3][r])));
#pragma unroll
            for (int m = 1; m < 16; m <<= 1) {
                s_ += __shfl_xor(s_, m, 64);
                q_ += __shfl_xor(q_, m, 64);
            }
            const float mean = s_ * (1.0f / 64.0f);
            const float var  = q_ * (1.0f / 64.0f) - mean * mean;
            const float rs   = rsqrtf(var + 1e-5f);
            const int p = p0 + prow + r;

            f32x4 y;
            y[0] = fmaxf((h[0][r] - mean) * rs * g4.x + bt4.x, 0.f);
            y[1] = fmaxf((h[1][r] - mean) * rs * g4.y + bt4.y, 0.f);
            y[2] = fmaxf((h[2][r] - mean) * rs * g4.z + bt4.z, 0.f);
            y[3] = fmaxf((h[3][r] - mean) * rs * g4.w + bt4.w, 0.f);
            __builtin_nontemporal_store(y, reinterpret_cast<f32x4*>(out + (size_t)p * C + 4 * chb));
        }

        const int pn = p0 + 16;
        if (pn < p_end && pn >= osh[seg]) {
            while (pn >= osh[seg]) ++seg;
            vb = *reinterpret_cast<const float4*>(vl + seg * C + 4 * chb);
        }
    }
}

extern "C" void kernel_launch(void* const* d_in, const int* in_sizes, int n_in,
                              void* d_out, int out_size, void* d_ws, size_t ws_size,
                              hipStream_t stream) {
    const float* x     = (const float*)d_in[0];
    const int*   o     = (const int*)d_in[1];
    const float* W2    = (const float*)d_in[2];
    const float* b2    = (const float*)d_in[3];
    const float* W1    = (const float*)d_in[4];
    const float* b1    = (const float*)d_in[5];
    const float* gamma = (const float*)d_in[6];
    const float* beta  = (const float*)d_in[7];
    float* out = (float*)d_out;

    const int N = in_sizes[0] / C;

    float* sums = (float*)d_ws;   // 1024 f32

    (void)hipMemsetAsync(sums, 0, B * C * sizeof(float), stream);

    const int rpb = 512;
    const int gridA = (N + rpb - 1) / rpb;
    seg_sum_kernel<<<gridA, 256, 0, stream>>>(x, o, sums, N, rpb);

    const int rpw = 128;
    const int ngw = (N + rpw - 1) / rpw;
    const int gridC = (ngw + 3) / 4;
    main_mfma_kernel<<<gridC, 256, 0, stream>>>(x, o, sums, W2, b2, W1, b1,
                                                gamma, beta, out, N, rpw, ngw);
}

// Round 14
// 149.799 us; speedup vs baseline: 1.2547x; 1.0331x over previous
//
#include <hip/hip_runtime.h>
#include <hip/hip_bf16.h>
#include <cstddef>

constexpr int C = 64;   // channels
constexpr int B = 16;   // segments

typedef __attribute__((ext_vector_type(8))) short bf16x8;
typedef __attribute__((ext_vector_type(4))) float f32x4;
typedef __attribute__((ext_vector_type(4))) unsigned int u32x4;

__device__ inline unsigned short f2bf(float f) {
    unsigned u = __builtin_bit_cast(unsigned, f);
    unsigned r = (u + 0x7FFFu + ((u >> 16) & 1u)) >> 16;   // RNE
    return (unsigned short)r;
}

__device__ inline unsigned pk2(float a, float b) {
    __hip_bfloat162 t = __float22bfloat162_rn(float2{a, b});   // v_cvt_pk_bf16_f32
    unsigned u;
    __builtin_memcpy(&u, &t, 4);
    return u;
}

__device__ inline bf16x8 cvt8(float4 u, float4 v) {
    u32x4 r;
    r[0] = pk2(u.x, u.y);
    r[1] = pk2(u.z, u.w);
    r[2] = pk2(v.x, v.y);
    r[3] = pk2(v.z, v.w);
    return __builtin_bit_cast(bf16x8, r);
}

// ---------------- Kernel A: per-segment column sums (R6/R10-exact) ------------
// 16 col-groups (4 channels) x 16 row-offsets; normal cached float4 loads.
__global__ __launch_bounds__(256) void seg_sum_kernel(
    const float* __restrict__ x, const int* __restrict__ o,
    float* __restrict__ sums, int N, int rows_per_block)
{
    __shared__ float lsum[B * C];
    const int tid = threadIdx.x;
    for (int i = tid; i < B * C; i += 256) lsum[i] = 0.0f;
    __syncthreads();

    const int c4 = (tid & 15) * 4;
    const int r0 = tid >> 4;
    const int row_begin = blockIdx.x * rows_per_block;
    const int row_end   = min(N, row_begin + rows_per_block);

    float ax = 0.f, ay = 0.f, az = 0.f, aw = 0.f;
    int seg = 0;
    int endcur = o[0];

    for (int r = row_begin + r0; r < row_end; r += 16) {
        while (r >= endcur) {
            if (ax != 0.f || ay != 0.f || az != 0.f || aw != 0.f) {
                atomicAdd(&lsum[seg * C + c4 + 0], ax);
                atomicAdd(&lsum[seg * C + c4 + 1], ay);
                atomicAdd(&lsum[seg * C + c4 + 2], az);
                atomicAdd(&lsum[seg * C + c4 + 3], aw);
                ax = ay = az = aw = 0.f;
            }
            ++seg;
            endcur = o[seg];
        }
        const float4 v = *reinterpret_cast<const float4*>(x + (size_t)r * C + c4);
        ax += v.x; ay += v.y; az += v.z; aw += v.w;
    }
    if (ax != 0.f || ay != 0.f || az != 0.f || aw != 0.f) {
        atomicAdd(&lsum[seg * C + c4 + 0], ax);
        atomicAdd(&lsum[seg * C + c4 + 1], ay);
        atomicAdd(&lsum[seg * C + c4 + 2], az);
        atomicAdd(&lsum[seg * C + c4 + 3], aw);
    }
    __syncthreads();

    for (int i = tid; i < B * C; i += 256) {
        const float v = lsum[i];
        if (v != 0.f) atomicAdd(&sums[i], v);
    }
}

// ---------------- Kernel C: fused MLP-prologue + MFMA main pass (R10-exact) ----
// LDS-squeezed (~12.2KB -> 8 blocks/CU); normal x loads; NT out stores.
__global__ __launch_bounds__(256) void main_mfma_kernel(
    const float* __restrict__ x, const int* __restrict__ o,
    const float* __restrict__ sums,
    const float* __restrict__ W2, const float* __restrict__ b2,
    const float* __restrict__ W1, const float* __restrict__ b1,
    const float* __restrict__ gamma, const float* __restrict__ beta,
    float* __restrict__ out, int N, int rows_per_wave, int ngw)
{
    __shared__ float smem[3 * B * C];
    __shared__ int osh[B];
    float* ms  = smem;                 // means
    float* xbs = smem + B * C;         // hidden
    float* vl  = smem + 2 * B * C;     // per-segment bias table
    unsigned short* wbfs = (unsigned short*)smem;  // 4096 bf16 = 8KB over ms+xbs

    const int tid = threadIdx.x;
    if (tid < B) osh[tid] = o[tid];
    __syncthreads();

    const int j = tid & 63;                // fixed channel per thread
    const int bq = tid >> 6;               // 0..3: quarter of segments

#pragma unroll
    for (int q = 0; q < 4; ++q) {
        const int b = bq * 4 + q;
        const int cnt = osh[b] - (b ? osh[b - 1] : 0);
        ms[b * C + j] = sums[b * C + j] / (float)cnt;
    }
    __syncthreads();

    {
        float acc[4];
        const float bj = b2[j];
#pragma unroll
        for (int q = 0; q < 4; ++q) acc[q] = bj;
        for (int c = 0; c < C; ++c) {
            const float wv = W2[c * C + j];
#pragma unroll
            for (int q = 0; q < 4; ++q)
                acc[q] = fmaf(ms[(bq * 4 + q) * C + c], wv, acc[q]);
        }
        __syncthreads();
#pragma unroll
        for (int q = 0; q < 4; ++q) xbs[(bq * 4 + q) * C + j] = fmaxf(acc[q], 0.f);
    }
    __syncthreads();

    {
        float acc[4];
        const float bj = b1[j];
#pragma unroll
        for (int q = 0; q < 4; ++q) acc[q] = bj;
        for (int jj = 0; jj < C; ++jj) {
            const float wv = W1[(C + jj) * C + j];
#pragma unroll
            for (int q = 0; q < 4; ++q)
                acc[q] = fmaf(xbs[(bq * 4 + q) * C + jj], wv, acc[q]);
        }
#pragma unroll
        for (int q = 0; q < 4; ++q) vl[(bq * 4 + q) * C + j] = acc[q];
    }
    __syncthreads();   // xbs dead from here; wbfs may overwrite ms+xbs

    for (int idx = tid; idx < 4096; idx += 256) {
        const int jj2 = idx & 7;
        const int ln  = (idx >> 3) & 63;
        const int tt  = (idx >> 9) & 1;
        const int ct  = idx >> 10;
        const int k   = tt * 32 + ((ln >> 4) * 8) + jj2;
        const int ch  = 4 * (ln & 15) + ct;          // permuted channel
        wbfs[idx] = f2bf(W1[k * C + ch]);
    }
    __syncthreads();

    const int lane = tid & 63;
    const int wid  = tid >> 6;
    const int chb  = lane & 15;
    const int prow = (lane >> 4) * 4;

    bf16x8 wf[4][2];
#pragma unroll
    for (int ct = 0; ct < 4; ++ct)
#pragma unroll
        for (int t = 0; t < 2; ++t)
            wf[ct][t] = *reinterpret_cast<const bf16x8*>(wbfs + ((ct * 2 + t) * 64 + lane) * 8);

    const float4 g4  = *reinterpret_cast<const float4*>(gamma + 4 * chb);
    const float4 bt4 = *reinterpret_cast<const float4*>(beta  + 4 * chb);

    const int gw = blockIdx.x * 4 + wid;
    if (gw >= ngw) return;
    const int p_begin = gw * rows_per_wave;
    if (p_begin >= N) return;
    const int p_end = min(N, p_begin + rows_per_wave);

    int seg = 0;
    while (p_begin >= osh[seg]) ++seg;
    float4 vb = *reinterpret_cast<const float4*>(vl + seg * C + 4 * chb);

    for (int p0 = p_begin; p0 < p_end; p0 += 16) {
        const float* xr = x + (size_t)(p0 + chb) * C + ((lane >> 4) * 8);
        const float4 a0 = *reinterpret_cast<const float4*>(xr);
        const float4 a1 = *reinterpret_cast<const float4*>(xr + 4);
        const float4 a2 = *reinterpret_cast<const float4*>(xr + 32);
        const float4 a3 = *reinterpret_cast<const float4*>(xr + 36);
        const bf16x8 A0 = cvt8(a0, a1);
        const bf16x8 A1 = cvt8(a2, a3);

        f32x4 acc[4];
#pragma unroll
        for (int ct = 0; ct < 4; ++ct) {
            acc[ct] = f32x4{0.f, 0.f, 0.f, 0.f};
            acc[ct] = __builtin_amdgcn_mfma_f32_16x16x32_bf16(A0, wf[ct][0], acc[ct], 0, 0, 0);
            acc[ct] = __builtin_amdgcn_mfma_f32_16x16x32_bf16(A1, wf[ct][1], acc[ct], 0, 0, 0);
        }

        float h[4][4];   // [ct][reg]
        if (p0 + 16 <= osh[seg]) {
#pragma unroll
            for (int r = 0; r < 4; ++r) {
                h[0][r] = acc[0][r] + vb.x;
                h[1][r] = acc[1][r] + vb.y;
                h[2][r] = acc[2][r] + vb.z;
                h[3][r] = acc[3][r] + vb.w;
            }
        } else {
#pragma unroll
            for (int r = 0; r < 4; ++r) {
                const int p = p0 + prow + r;
                int s = seg;
                while (p >= osh[s]) ++s;
                const float4 vbs = *reinterpret_cast<const float4*>(vl + s * C + 4 * chb);
                h[0][r] = acc[0][r] + vbs.x;
                h[1][r] = acc[1][r] + vbs.y;
                h[2][r] = acc[2][r] + vbs.z;
                h[3][r] = acc[3][r] + vbs.w;
            }
        }

#pragma unroll
        for (int r = 0; r < 4; ++r) {
            float s_ = (h[0][r] + h[1][r]) + (h[2][r] + h[3][r]);
            float q_ = fmaf(h[0][r], h[0][r],
                       fmaf(h[1][r], h[1][r],
                       fmaf(h[2][r], h[2][r], h[3][r] * h[3][r])));
#pragma unroll
            for (int m = 1; m < 16; m <<= 1) {
                s_ += __shfl_xor(s_, m, 64);
                q_ += __shfl_xor(q_, m, 64);
            }
            const float mean = s_ * (1.0f / 64.0f);
            const float var  = q_ * (1.0f / 64.0f) - mean * mean;
            const float rs   = rsqrtf(var + 1e-5f);
            const int p = p0 + prow + r;

            f32x4 y;
            y[0] = fmaxf((h[0][r] - mean) * rs * g4.x + bt4.x, 0.f);
            y[1] = fmaxf((h[1][r] - mean) * rs * g4.y + bt4.y, 0.f);
            y[2] = fmaxf((h[2][r] - mean) * rs * g4.z + bt4.z, 0.f);
            y[3] = fmaxf((h[3][r] - mean) * rs * g4.w + bt4.w, 0.f);
            __builtin_nontemporal_store(y, reinterpret_cast<f32x4*>(out + (size_t)p * C + 4 * chb));
        }

        const int pn = p0 + 16;
        if (pn < p_end && pn >= osh[seg]) {
            while (pn >= osh[seg]) ++seg;
            vb = *reinterpret_cast<const float4*>(vl + seg * C + 4 * chb);
        }
    }
}

extern "C" void kernel_launch(void* const* d_in, const int* in_sizes, int n_in,
                              void* d_out, int out_size, void* d_ws, size_t ws_size,
                              hipStream_t stream) {
    const float* x     = (const float*)d_in[0];
    const int*   o     = (const int*)d_in[1];
    const float* W2    = (const float*)d_in[2];
    const float* b2    = (const float*)d_in[3];
    const float* W1    = (const float*)d_in[4];
    const float* b1    = (const float*)d_in[5];
    const float* gamma = (const float*)d_in[6];
    const float* beta  = (const float*)d_in[7];
    float* out = (float*)d_out;

    const int N = in_sizes[0] / C;

    float* sums = (float*)d_ws;   // 1024 f32

    (void)hipMemsetAsync(sums, 0, B * C * sizeof(float), stream);

    const int rpb = 512;
    const int gridA = (N + rpb - 1) / rpb;
    seg_sum_kernel<<<gridA, 256, 0, stream>>>(x, o, sums, N, rpb);

    const int rpw = 128;
    const int ngw = (N + rpw - 1) / rpw;
    const int gridC = (ngw + 3) / 4;
    main_mfma_kernel<<<gridC, 256, 0, stream>>>(x, o, sums, W2, b2, W1, b1,
                                                gamma, beta, out, N, rpw, ngw);
}